// Round 3
// baseline (496.525 us; speedup 1.0000x reference)
//
#include <hip/hip_runtime.h>
#include <hip/hip_bf16.h>
#include <stdint.h>

#define S_LEN 2048
#define DMODEL 1024
#define NH 16
#define HD 64
// scale: 1/sqrt(64) folded with log2(e) for v_exp_f32 (exp2)
#define SC2 0.18033688011112042f

typedef __attribute__((ext_vector_type(8))) short bf16x8;
typedef __attribute__((ext_vector_type(4))) float f32x4;
typedef unsigned long long u64;

__device__ __forceinline__ void gload16(const void* g, void* l) {
  __builtin_amdgcn_global_load_lds(
      reinterpret_cast<const __attribute__((address_space(1))) void*>(reinterpret_cast<uintptr_t>(g)),
      reinterpret_cast<__attribute__((address_space(3))) void*>(reinterpret_cast<uintptr_t>(l)),
      16, 0, 0);
}

__device__ __forceinline__ f32x4 mfma_bf16(bf16x8 a, bf16x8 b, f32x4 c) {
  return __builtin_amdgcn_mfma_f32_16x16x32_bf16(a, b, c, 0, 0, 0);
}

__device__ __forceinline__ unsigned short bfbits(float x) {
  __hip_bfloat16 h = __float2bfloat16(x);
  return *reinterpret_cast<unsigned short*>(&h);
}

__device__ __forceinline__ float asf(unsigned u) {
  union { unsigned u; float f; } c; c.u = u; return c.f;
}

// ---------------- convert ip f32 -> bf16 ----------------
__global__ __launch_bounds__(256) void k_convert_ip(const float* __restrict__ in,
                                                    __hip_bfloat16* __restrict__ out, int n) {
  int i = (blockIdx.x * 256 + threadIdx.x) * 4;
  if (i >= n) return;
  f32x4 v = *(const f32x4*)(in + i);
  u64 p = (u64)bfbits(v[0]) | ((u64)bfbits(v[1]) << 16) | ((u64)bfbits(v[2]) << 32)
        | ((u64)bfbits(v[3]) << 48);
  *reinterpret_cast<u64*>(out + i) = p;
}

// ---------------- transpose+convert weights: out[n][k] = in[k][n] (1024x1024) ----------------
__global__ __launch_bounds__(1024) void k_transpose_w(const float* __restrict__ wq,
                                                      const float* __restrict__ wk,
                                                      const float* __restrict__ wv,
                                                      const float* __restrict__ fcw,
                                                      __hip_bfloat16* __restrict__ wt_all,
                                                      __hip_bfloat16* __restrict__ fct) {
  __shared__ float tile[32][33];
  const int z = blockIdx.z;
  const float* src = (z == 0) ? wq : (z == 1) ? wk : (z == 2) ? wv : fcw;
  __hip_bfloat16* dst = (z == 3) ? fct : wt_all + (size_t)z * DMODEL * DMODEL;
  const int kb = blockIdx.y * 32, nb = blockIdx.x * 32;
  tile[threadIdx.y][threadIdx.x] = src[(size_t)(kb + threadIdx.y) * DMODEL + nb + threadIdx.x];
  __syncthreads();
  dst[(size_t)(nb + threadIdx.y) * DMODEL + kb + threadIdx.x] =
      __float2bfloat16(tile[threadIdx.x][threadIdx.y]);
}

// ---------------- transpose V [bh][s][d] -> Vt [bh][d][s] (bf16) ----------------
__global__ __launch_bounds__(1024) void k_transpose_v(const unsigned short* __restrict__ V,
                                                      unsigned short* __restrict__ Vt) {
  __shared__ unsigned short tile[32][33];
  const int bh = blockIdx.z;
  const int sb = blockIdx.x * 32, db = blockIdx.y * 32;
  const unsigned short* src = V + (size_t)bh * S_LEN * HD;
  unsigned short* dst = Vt + (size_t)bh * HD * S_LEN;
  tile[threadIdx.y][threadIdx.x] = src[(size_t)(sb + threadIdx.y) * HD + db + threadIdx.x];
  __syncthreads();
  dst[(size_t)(db + threadIdx.y) * S_LEN + sb + threadIdx.x] = tile[threadIdx.x][threadIdx.y];
}

// ---------------- bf16 GEMM, 128x128 tile, BK=32, 4 waves (m97 structure) ----------------
template <int MODE>
__global__ __launch_bounds__(256) void k_gemm(const __hip_bfloat16* __restrict__ A,
                                              const __hip_bfloat16* __restrict__ Bt,
                                              __hip_bfloat16* __restrict__ Q,
                                              __hip_bfloat16* __restrict__ Kk,
                                              __hip_bfloat16* __restrict__ V,
                                              const float* __restrict__ ipf,
                                              const float* __restrict__ bias,
                                              float* __restrict__ preln) {
  __shared__ __align__(128) char lds[16384];
  char* Al = lds;
  char* Bl = lds + 8192;
  const int t = threadIdx.x;
  const int w = t >> 6, l = t & 63;
  const int g = l >> 4, lr = l & 15;
  const int bm = blockIdx.x & 31;
  const int bn = blockIdx.x >> 5;

  int sr0 = (w * 2 + 0) * 16 + (l >> 2);
  int sr1 = (w * 2 + 1) * 16 + (l >> 2);
  const int sc = (l & 3) * 16;
  const char* aSrc0 = (const char*)A + ((size_t)(bm * 128 + sr0)) * 2048 + (sc ^ (((sr0 >> 1) & 3) << 4));
  const char* aSrc1 = (const char*)A + ((size_t)(bm * 128 + sr1)) * 2048 + (sc ^ (((sr1 >> 1) & 3) << 4));
  const char* bSrc0 = (const char*)Bt + ((size_t)(bn * 128 + sr0)) * 2048 + (sc ^ (((sr0 >> 1) & 3) << 4));
  const char* bSrc1 = (const char*)Bt + ((size_t)(bn * 128 + sr1)) * 2048 + (sc ^ (((sr1 >> 1) & 3) << 4));

  const int wm = (w >> 1) * 64, wn = (w & 1) * 64;
  int roff[4], noff[4];
#pragma unroll
  for (int mi = 0; mi < 4; ++mi) {
    int m = wm + mi * 16 + lr;
    roff[mi] = m * 64 + ((g * 16) ^ (((m >> 1) & 3) << 4));
  }
#pragma unroll
  for (int ni = 0; ni < 4; ++ni) {
    int n = wn + ni * 16 + lr;
    noff[ni] = n * 64 + ((g * 16) ^ (((n >> 1) & 3) << 4));
  }

  f32x4 acc[4][4] = {};
  for (int k0 = 0; k0 < DMODEL; k0 += 32) {
    gload16(aSrc0 + k0 * 2, Al + (w * 2 + 0) * 1024);
    gload16(aSrc1 + k0 * 2, Al + (w * 2 + 1) * 1024);
    gload16(bSrc0 + k0 * 2, Bl + (w * 2 + 0) * 1024);
    gload16(bSrc1 + k0 * 2, Bl + (w * 2 + 1) * 1024);
    __syncthreads();
    bf16x8 af[4], bfv[4];
#pragma unroll
    for (int mi = 0; mi < 4; ++mi) af[mi] = *(const bf16x8*)(Al + roff[mi]);
#pragma unroll
    for (int ni = 0; ni < 4; ++ni) bfv[ni] = *(const bf16x8*)(Bl + noff[ni]);
#pragma unroll
    for (int mi = 0; mi < 4; ++mi)
#pragma unroll
      for (int ni = 0; ni < 4; ++ni)
        acc[mi][ni] = mfma_bf16(af[mi], bfv[ni], acc[mi][ni]);
    __syncthreads();
  }

#pragma unroll
  for (int mi = 0; mi < 4; ++mi)
#pragma unroll
    for (int ni = 0; ni < 4; ++ni) {
      f32x4 v = acc[mi][ni];
#pragma unroll
      for (int r = 0; r < 4; ++r) {
        int m = bm * 128 + wm + mi * 16 + g * 4 + r;
        int n = bn * 128 + wn + ni * 16 + lr;
        if (MODE == 0) {
          int mat = n >> 10, c = n & 1023;
          int h = c >> 6, d = c & 63;
          int b = m >> 11, s = m & 2047;
          size_t idx = (((size_t)(b * NH + h)) * S_LEN + s) * HD + d;
          __hip_bfloat16 hv = __float2bfloat16(v[r]);
          if (mat == 0) Q[idx] = hv;
          else if (mat == 1) Kk[idx] = hv;
          else V[idx] = hv;
        } else {
          size_t idx = (size_t)m * DMODEL + n;
          preln[idx] = v[r] + bias[n] + ipf[idx];
        }
      }
    }
}

// ---------------- flash attention (ctx only): single kv sweep, no-max online softmax ----
// grid (64 q-tiles of 32, 32 bh), block 256: wave w -> qg=w>>1 (16 q rows), half=w&1 (1024 kv).
// o_acc = sum exp(s)*V (unnormalized), lsum accumulated; cross-half LDS reduce; /lsum at end.
__global__ __launch_bounds__(256, 8) void k_flash(const __hip_bfloat16* __restrict__ Q,
                                                  const __hip_bfloat16* __restrict__ K,
                                                  const __hip_bfloat16* __restrict__ Vt,
                                                  float* __restrict__ invl,
                                                  __hip_bfloat16* __restrict__ ctx) {
  __shared__ __align__(128) char pool[4][2048];  // per-wave P tile [16 q][64 kv] bf16; reused for o-reduce
  __shared__ float lred[2][2][16];               // [qg][half][q] row sums
  const int t = threadIdx.x, w = t >> 6, l = t & 63;
  const int g = l >> 4, lr = l & 15;
  const int qg = w >> 1, half = w & 1;
  char* plds = &pool[w][0];
  const int bh = blockIdx.y;
  const int b = bh >> 4, h = bh & 15;
  const int q0 = blockIdx.x * 32 + qg * 16;
  const __hip_bfloat16* Qh = Q + (size_t)bh * S_LEN * HD;
  const __hip_bfloat16* Kh = K + (size_t)bh * S_LEN * HD;
  const __hip_bfloat16* Vh = Vt + (size_t)bh * HD * S_LEN;

  bf16x8 qf0 = *(const bf16x8*)(Qh + (size_t)(q0 + lr) * HD + 8 * g);
  bf16x8 qf1 = *(const bf16x8*)(Qh + (size_t)(q0 + lr) * HD + 32 + 8 * g);

  const int prow = lr * 128;       // 128B rows ([16][64] bf16)
  const int pswz = (lr & 7) << 4;  // XOR swizzle on byte bits 4-6
  float lsum = 0.f;
  f32x4 o[4] = {};
  const int kvbase = half * 1024;

  for (int kv0 = kvbase; kv0 < kvbase + 1024; kv0 += 64) {
#pragma unroll
    for (int tt = 0; tt < 4; ++tt) {
      int kv = kv0 + tt * 16;
      bf16x8 kf0 = *(const bf16x8*)(Kh + (size_t)(kv + lr) * HD + 8 * g);
      bf16x8 kf1 = *(const bf16x8*)(Kh + (size_t)(kv + lr) * HD + 32 + 8 * g);
      f32x4 s = {};
      s = mfma_bf16(kf0, qf0, s);  // D[kv][q]: lane holds q=lr, kv=4g+r
      s = mfma_bf16(kf1, qf1, s);
      float p0 = __builtin_amdgcn_exp2f(s[0] * SC2);
      float p1 = __builtin_amdgcn_exp2f(s[1] * SC2);
      float p2 = __builtin_amdgcn_exp2f(s[2] * SC2);
      float p3 = __builtin_amdgcn_exp2f(s[3] * SC2);
      lsum += (p0 + p1) + (p2 + p3);
      u64 u = (u64)bfbits(p0) | ((u64)bfbits(p1) << 16) | ((u64)bfbits(p2) << 32)
            | ((u64)bfbits(p3) << 48);
      *reinterpret_cast<u64*>(plds + prow + ((tt * 32 + g * 8) ^ pswz)) = u;
    }
    bf16x8 pf0 = *(const bf16x8*)(plds + prow + ((g * 16) ^ pswz));
    bf16x8 pf1 = *(const bf16x8*)(plds + prow + ((64 + g * 16) ^ pswz));
#pragma unroll
    for (int dvt = 0; dvt < 4; ++dvt) {
      bf16x8 vf0 = *(const bf16x8*)(Vh + (size_t)(dvt * 16 + lr) * S_LEN + kv0 + 8 * g);
      bf16x8 vf1 = *(const bf16x8*)(Vh + (size_t)(dvt * 16 + lr) * S_LEN + kv0 + 32 + 8 * g);
      o[dvt] = mfma_bf16(pf0, vf0, o[dvt]);
      o[dvt] = mfma_bf16(pf1, vf1, o[dvt]);
    }
  }

  lsum += __shfl_xor(lsum, 16);
  lsum += __shfl_xor(lsum, 32);  // all lanes: row sum for q=lr over this half
  if (l < 16) lred[qg][half][l] = lsum;
  __syncthreads();  // all P tiles dead, lred visible
  if (half == 1) {
#pragma unroll
    for (int dvt = 0; dvt < 4; ++dvt)
      *(f32x4*)(&pool[0][0] + qg * 4096 + l * 64 + dvt * 16) = o[dvt];
  }
  __syncthreads();
  if (half == 0) {
    f32x4 la = *(const f32x4*)(&lred[qg][0][g * 4]);
    f32x4 lb = *(const f32x4*)(&lred[qg][1][g * 4]);
    f32x4 inv;
#pragma unroll
    for (int r = 0; r < 4; ++r) inv[r] = 1.0f / (la[r] + lb[r]);
#pragma unroll
    for (int dvt = 0; dvt < 4; ++dvt) {
      f32x4 part = *(const f32x4*)(&pool[0][0] + qg * 4096 + l * 64 + dvt * 16);
#pragma unroll
      for (int r = 0; r < 4; ++r) {
        int q = q0 + g * 4 + r;
        size_t idx = ((size_t)b * S_LEN + q) * DMODEL + h * HD + dvt * 16 + lr;
        ctx[idx] = __float2bfloat16((o[dvt][r] + part[r]) * inv[r]);
      }
    }
    if (l < 16) invl[(size_t)bh * S_LEN + q0 + l] = 1.0f / (lred[qg][0][l] + lred[qg][1][l]);
  }
}

// ---------------- attn writer: recompute QK^T, scale by invl, NT coalesced f32 stores ----
// grid (32 q-blocks of 64, 4 kv-blocks of 512, 32 bh), block 256 (4 waves x 16 q).
__global__ __launch_bounds__(256, 8) void k_awrite(const __hip_bfloat16* __restrict__ Q,
                                                   const __hip_bfloat16* __restrict__ K,
                                                   const float* __restrict__ invl,
                                                   float* __restrict__ attn) {
  __shared__ __align__(128) char plds_all[4][4096];  // per-wave [16 q][128 kv] bf16, swizzled
  const int t = threadIdx.x, w = t >> 6, l = t & 63;
  const int g = l >> 4, lr = l & 15;
  char* plds = &plds_all[w][0];
  const int bh = blockIdx.z;
  const int q0 = blockIdx.x * 64 + w * 16;
  const int kvb = blockIdx.y * 512;
  const __hip_bfloat16* Qh = Q + (size_t)bh * S_LEN * HD;
  const __hip_bfloat16* Kh = K + (size_t)bh * S_LEN * HD;

  bf16x8 qf0 = *(const bf16x8*)(Qh + (size_t)(q0 + lr) * HD + 8 * g);
  bf16x8 qf1 = *(const bf16x8*)(Qh + (size_t)(q0 + lr) * HD + 32 + 8 * g);
  const float inv = invl[(size_t)bh * S_LEN + q0 + lr];

  const int prow = lr * 256;
  const int pswz = (lr & 7) << 4;
  const int rb_half = l >> 5, rb_col = l & 31;

  for (int kv0 = kvb; kv0 < kvb + 512; kv0 += 128) {
#pragma unroll
    for (int tt = 0; tt < 8; ++tt) {
      int kv = kv0 + tt * 16;
      bf16x8 kf0 = *(const bf16x8*)(Kh + (size_t)(kv + lr) * HD + 8 * g);
      bf16x8 kf1 = *(const bf16x8*)(Kh + (size_t)(kv + lr) * HD + 32 + 8 * g);
      f32x4 s = {};
      s = mfma_bf16(kf0, qf0, s);
      s = mfma_bf16(kf1, qf1, s);
      float p0 = __builtin_amdgcn_exp2f(s[0] * SC2) * inv;
      float p1 = __builtin_amdgcn_exp2f(s[1] * SC2) * inv;
      float p2 = __builtin_amdgcn_exp2f(s[2] * SC2) * inv;
      float p3 = __builtin_amdgcn_exp2f(s[3] * SC2) * inv;
      u64 u = (u64)bfbits(p0) | ((u64)bfbits(p1) << 16) | ((u64)bfbits(p2) << 32)
            | ((u64)bfbits(p3) << 48);
      *reinterpret_cast<u64*>(plds + prow + ((tt * 32 + g * 8) ^ pswz)) = u;
    }
    // coalesced readback: 2 rows x 512B per store instruction, nontemporal
#pragma unroll
    for (int i = 0; i < 8; ++i) {
      int row = 2 * i + rb_half;
      u64 v = *reinterpret_cast<const u64*>(plds + row * 256 + ((rb_col * 8) ^ ((row & 7) << 4)));
      unsigned lo = (unsigned)v, hi = (unsigned)(v >> 32);
      f32x4 pv;
      pv[0] = asf(lo << 16);
      pv[1] = asf(lo & 0xffff0000u);
      pv[2] = asf(hi << 16);
      pv[3] = asf(hi & 0xffff0000u);
      __builtin_nontemporal_store(
          pv, (f32x4*)(attn + ((size_t)bh * S_LEN + q0 + row) * S_LEN + kv0 + rb_col * 4));
    }
  }
}

// ---------------- LayerNorm over rows of 1024 ----------------
__global__ __launch_bounds__(256) void k_ln(const float* __restrict__ x,
                                            const float* __restrict__ gam,
                                            const float* __restrict__ bet,
                                            float* __restrict__ y) {
  const int row = blockIdx.x;
  const int i = threadIdx.x * 4;
  const float* xr = x + (size_t)row * DMODEL;
  f32x4 v = *(const f32x4*)(xr + i);
  float s = v[0] + v[1] + v[2] + v[3];
  float s2 = v[0] * v[0] + v[1] * v[1] + v[2] * v[2] + v[3] * v[3];
#pragma unroll
  for (int off = 1; off < 64; off <<= 1) {
    s += __shfl_xor(s, off);
    s2 += __shfl_xor(s2, off);
  }
  __shared__ float red[2][4];
  const int w = threadIdx.x >> 6, ln = threadIdx.x & 63;
  if (ln == 0) { red[0][w] = s; red[1][w] = s2; }
  __syncthreads();
  s = red[0][0] + red[0][1] + red[0][2] + red[0][3];
  s2 = red[1][0] + red[1][1] + red[1][2] + red[1][3];
  const float mu = s * (1.f / DMODEL);
  const float rstd = rsqrtf(s2 * (1.f / DMODEL) - mu * mu + 1e-6f);
  f32x4 gv = *(const f32x4*)(gam + i), bv = *(const f32x4*)(bet + i);
  f32x4 out;
#pragma unroll
  for (int j = 0; j < 4; ++j) out[j] = (v[j] - mu) * rstd * gv[j] + bv[j];
  *(f32x4*)(y + (size_t)row * DMODEL + i) = out;
}

extern "C" void kernel_launch(void* const* d_in, const int* in_sizes, int n_in,
                              void* d_out, int out_size, void* d_ws, size_t ws_size,
                              hipStream_t stream) {
  const float* ip  = (const float*)d_in[0];
  const float* wk  = (const float*)d_in[1];
  const float* wq  = (const float*)d_in[2];
  const float* wv  = (const float*)d_in[3];
  const float* fcw = (const float*)d_in[4];
  const float* fcb = (const float*)d_in[5];
  const float* lng = (const float*)d_in[6];
  const float* lnb = (const float*)d_in[7];

  float* y = (float*)d_out;
  float* attn = y + (size_t)2 * S_LEN * DMODEL;  // outputs concatenated (y, attn)

  char* ws = (char*)d_ws;
  __hip_bfloat16* ipb = (__hip_bfloat16*)(ws);                  //  8 MB: ip bf16
  __hip_bfloat16* wt  = (__hip_bfloat16*)(ws + (8ll << 20));    //  6 MB: [wq^T|wk^T|wv^T]
  __hip_bfloat16* fct = (__hip_bfloat16*)(ws + (14ll << 20));   //  2 MB: fc_w^T
  __hip_bfloat16* Qb  = (__hip_bfloat16*)(ws + (16ll << 20));   //  8 MB: Q [32 bh][2048][64]
  __hip_bfloat16* Kb  = (__hip_bfloat16*)(ws + (24ll << 20));   //  8 MB: K
  __hip_bfloat16* Vb  = (__hip_bfloat16*)(ws + (32ll << 20));   //  8 MB: V
  __hip_bfloat16* Vtb = (__hip_bfloat16*)(ws + (40ll << 20));   //  8 MB: V^T [32 bh][64][2048]
  __hip_bfloat16* ctx = (__hip_bfloat16*)(ws + (48ll << 20));   //  8 MB: ctx
  float* preln        = (float*)(ws + (56ll << 20));            // 16 MB: pre-LN f32
  float* invl         = (float*)(ws + (72ll << 20));            // 256 KB: 1/lsum per (bh,q)

  k_convert_ip<<<4096, 256, 0, stream>>>(ip, ipb, 2 * S_LEN * DMODEL);
  k_transpose_w<<<dim3(32, 32, 4), dim3(32, 32), 0, stream>>>(wq, wk, wv, fcw, wt, fct);
  k_gemm<0><<<32 * 24, 256, 0, stream>>>(ipb, wt, Qb, Kb, Vb, nullptr, nullptr, nullptr);
  k_transpose_v<<<dim3(64, 2, 32), dim3(32, 32), 0, stream>>>((const unsigned short*)Vb,
                                                              (unsigned short*)Vtb);
  k_flash<<<dim3(64, 32), 256, 0, stream>>>(Qb, Kb, Vtb, invl, ctx);
  k_awrite<<<dim3(32, 4, 32), 256, 0, stream>>>(Qb, Kb, invl, attn);
  k_gemm<1><<<32 * 8, 256, 0, stream>>>(ctx, fct, nullptr, nullptr, nullptr, ip, fcb, preln);
  k_ln<<<4096, 256, 0, stream>>>(preln, lng, lnb, y);
}

// Round 4
// 352.903 us; speedup vs baseline: 1.4070x; 1.4070x over previous
//
#include <hip/hip_runtime.h>
#include <hip/hip_bf16.h>
#include <stdint.h>

#define S_LEN 2048
#define DMODEL 1024
#define NH 16
#define HD 64
// scale: 1/sqrt(64) folded with log2(e) for v_exp_f32 (exp2)
#define SC2 0.18033688011112042f

typedef __attribute__((ext_vector_type(8))) short bf16x8;
typedef __attribute__((ext_vector_type(4))) float f32x4;
typedef unsigned long long u64;

__device__ __forceinline__ void gload16(const void* g, void* l) {
  __builtin_amdgcn_global_load_lds(
      reinterpret_cast<const __attribute__((address_space(1))) void*>(reinterpret_cast<uintptr_t>(g)),
      reinterpret_cast<__attribute__((address_space(3))) void*>(reinterpret_cast<uintptr_t>(l)),
      16, 0, 0);
}

__device__ __forceinline__ f32x4 mfma_bf16(bf16x8 a, bf16x8 b, f32x4 c) {
  return __builtin_amdgcn_mfma_f32_16x16x32_bf16(a, b, c, 0, 0, 0);
}

__device__ __forceinline__ unsigned short bfbits(float x) {
  __hip_bfloat16 h = __float2bfloat16(x);
  return *reinterpret_cast<unsigned short*>(&h);
}

__device__ __forceinline__ float asf(unsigned u) {
  union { unsigned u; float f; } c; c.u = u; return c.f;
}

// ---------------- convert ip f32 -> bf16 ----------------
__global__ __launch_bounds__(256) void k_convert_ip(const float* __restrict__ in,
                                                    __hip_bfloat16* __restrict__ out, int n) {
  int i = (blockIdx.x * 256 + threadIdx.x) * 4;
  if (i >= n) return;
  f32x4 v = *(const f32x4*)(in + i);
  u64 p = (u64)bfbits(v[0]) | ((u64)bfbits(v[1]) << 16) | ((u64)bfbits(v[2]) << 32)
        | ((u64)bfbits(v[3]) << 48);
  *reinterpret_cast<u64*>(out + i) = p;
}

// ---------------- transpose+convert weights: out[n][k] = in[k][n] (1024x1024) ----------------
__global__ __launch_bounds__(1024) void k_transpose_w(const float* __restrict__ wq,
                                                      const float* __restrict__ wk,
                                                      const float* __restrict__ wv,
                                                      const float* __restrict__ fcw,
                                                      __hip_bfloat16* __restrict__ wt_all,
                                                      __hip_bfloat16* __restrict__ fct) {
  __shared__ float tile[32][33];
  const int z = blockIdx.z;
  const float* src = (z == 0) ? wq : (z == 1) ? wk : (z == 2) ? wv : fcw;
  __hip_bfloat16* dst = (z == 3) ? fct : wt_all + (size_t)z * DMODEL * DMODEL;
  const int kb = blockIdx.y * 32, nb = blockIdx.x * 32;
  tile[threadIdx.y][threadIdx.x] = src[(size_t)(kb + threadIdx.y) * DMODEL + nb + threadIdx.x];
  __syncthreads();
  dst[(size_t)(nb + threadIdx.y) * DMODEL + kb + threadIdx.x] =
      __float2bfloat16(tile[threadIdx.x][threadIdx.y]);
}

// ---------------- transpose V [bh][s][d] -> Vt [bh][d][s] (bf16) ----------------
__global__ __launch_bounds__(1024) void k_transpose_v(const unsigned short* __restrict__ V,
                                                      unsigned short* __restrict__ Vt) {
  __shared__ unsigned short tile[32][33];
  const int bh = blockIdx.z;
  const int sb = blockIdx.x * 32, db = blockIdx.y * 32;
  const unsigned short* src = V + (size_t)bh * S_LEN * HD;
  unsigned short* dst = Vt + (size_t)bh * HD * S_LEN;
  tile[threadIdx.y][threadIdx.x] = src[(size_t)(sb + threadIdx.y) * HD + db + threadIdx.x];
  __syncthreads();
  dst[(size_t)(db + threadIdx.y) * S_LEN + sb + threadIdx.x] = tile[threadIdx.x][threadIdx.y];
}

// ---------------- bf16 GEMM, 128x128 tile, BK=32, 4 waves (m97 structure) ----------------
template <int MODE>
__global__ __launch_bounds__(256) void k_gemm(const __hip_bfloat16* __restrict__ A,
                                              const __hip_bfloat16* __restrict__ Bt,
                                              __hip_bfloat16* __restrict__ Q,
                                              __hip_bfloat16* __restrict__ Kk,
                                              __hip_bfloat16* __restrict__ V,
                                              const float* __restrict__ ipf,
                                              const float* __restrict__ bias,
                                              float* __restrict__ preln) {
  __shared__ __align__(128) char lds[16384];
  char* Al = lds;
  char* Bl = lds + 8192;
  const int t = threadIdx.x;
  const int w = t >> 6, l = t & 63;
  const int g = l >> 4, lr = l & 15;
  const int bm = blockIdx.x & 31;
  const int bn = blockIdx.x >> 5;

  int sr0 = (w * 2 + 0) * 16 + (l >> 2);
  int sr1 = (w * 2 + 1) * 16 + (l >> 2);
  const int sc = (l & 3) * 16;
  const char* aSrc0 = (const char*)A + ((size_t)(bm * 128 + sr0)) * 2048 + (sc ^ (((sr0 >> 1) & 3) << 4));
  const char* aSrc1 = (const char*)A + ((size_t)(bm * 128 + sr1)) * 2048 + (sc ^ (((sr1 >> 1) & 3) << 4));
  const char* bSrc0 = (const char*)Bt + ((size_t)(bn * 128 + sr0)) * 2048 + (sc ^ (((sr0 >> 1) & 3) << 4));
  const char* bSrc1 = (const char*)Bt + ((size_t)(bn * 128 + sr1)) * 2048 + (sc ^ (((sr1 >> 1) & 3) << 4));

  const int wm = (w >> 1) * 64, wn = (w & 1) * 64;
  int roff[4], noff[4];
#pragma unroll
  for (int mi = 0; mi < 4; ++mi) {
    int m = wm + mi * 16 + lr;
    roff[mi] = m * 64 + ((g * 16) ^ (((m >> 1) & 3) << 4));
  }
#pragma unroll
  for (int ni = 0; ni < 4; ++ni) {
    int n = wn + ni * 16 + lr;
    noff[ni] = n * 64 + ((g * 16) ^ (((n >> 1) & 3) << 4));
  }

  f32x4 acc[4][4] = {};
  for (int k0 = 0; k0 < DMODEL; k0 += 32) {
    gload16(aSrc0 + k0 * 2, Al + (w * 2 + 0) * 1024);
    gload16(aSrc1 + k0 * 2, Al + (w * 2 + 1) * 1024);
    gload16(bSrc0 + k0 * 2, Bl + (w * 2 + 0) * 1024);
    gload16(bSrc1 + k0 * 2, Bl + (w * 2 + 1) * 1024);
    __syncthreads();
    bf16x8 af[4], bfv[4];
#pragma unroll
    for (int mi = 0; mi < 4; ++mi) af[mi] = *(const bf16x8*)(Al + roff[mi]);
#pragma unroll
    for (int ni = 0; ni < 4; ++ni) bfv[ni] = *(const bf16x8*)(Bl + noff[ni]);
#pragma unroll
    for (int mi = 0; mi < 4; ++mi)
#pragma unroll
      for (int ni = 0; ni < 4; ++ni)
        acc[mi][ni] = mfma_bf16(af[mi], bfv[ni], acc[mi][ni]);
    __syncthreads();
  }

#pragma unroll
  for (int mi = 0; mi < 4; ++mi)
#pragma unroll
    for (int ni = 0; ni < 4; ++ni) {
      f32x4 v = acc[mi][ni];
#pragma unroll
      for (int r = 0; r < 4; ++r) {
        int m = bm * 128 + wm + mi * 16 + g * 4 + r;
        int n = bn * 128 + wn + ni * 16 + lr;
        if (MODE == 0) {
          int mat = n >> 10, c = n & 1023;
          int h = c >> 6, d = c & 63;
          int b = m >> 11, s = m & 2047;
          size_t idx = (((size_t)(b * NH + h)) * S_LEN + s) * HD + d;
          __hip_bfloat16 hv = __float2bfloat16(v[r]);
          if (mat == 0) Q[idx] = hv;
          else if (mat == 1) Kk[idx] = hv;
          else V[idx] = hv;
        } else {
          size_t idx = (size_t)m * DMODEL + n;
          preln[idx] = v[r] + bias[n] + ipf[idx];
        }
      }
    }
}

// ---------------- fused attention, one pass ----------------
// Block = 16 q rows x full 2048 kv for one (b,h). 4 waves; wave w owns kv
// quadrant [w*512, +512): QK^T -> exp (lsum online, no max) -> P(bf16) into a
// 16KB LDS tile -> PV from own tile. Then the block writes attn as ONE
// contiguous 128KB region (wave w streams rows 4w..4w+3 = 32KB sequential NT
// stores) -- long monotonic streams for DRAM page locality. Cross-wave o
// reduce in LDS -> ctx. XCD-aware bid mapping keeps each bh's 128 blocks on
// one XCD so K/V (512KB) stay L2-resident.
__global__ __launch_bounds__(256, 2) void k_attn2(const __hip_bfloat16* __restrict__ Q,
                                                  const __hip_bfloat16* __restrict__ K,
                                                  const __hip_bfloat16* __restrict__ Vt,
                                                  float* __restrict__ attn,
                                                  __hip_bfloat16* __restrict__ ctx) {
  __shared__ __align__(128) char ptile[4][16384];  // [wave][16 q][1024B], XOR-swizzled rows
  __shared__ float lred[4][16];
  __shared__ float linv[16];
  __shared__ f32x4 obuf[3][64][4];  // 12KB cross-wave o partials

  const int t = threadIdx.x, w = t >> 6, l = t & 63;
  const int g = l >> 4, lr = l & 15;
  const int bid = blockIdx.x;
  const int qc = (bid >> 3) & 127;          // q-chunk 0..127
  const int bh = (bid & 7) + 8 * (bid >> 10);  // XCD (bid&7) gets bh = x, 8+x, 16+x, 24+x
  const int b = bh >> 4, h = bh & 15;
  const int q0 = qc * 16;
  const __hip_bfloat16* Qh = Q + (size_t)bh * S_LEN * HD;
  const __hip_bfloat16* Kh = K + (size_t)bh * S_LEN * HD;
  const __hip_bfloat16* Vh = Vt + (size_t)bh * HD * S_LEN;

  bf16x8 qf0 = *(const bf16x8*)(Qh + (size_t)(q0 + lr) * HD + 8 * g);
  bf16x8 qf1 = *(const bf16x8*)(Qh + (size_t)(q0 + lr) * HD + 32 + 8 * g);

  char* myt = &ptile[w][0];
  const int pswz = (lr & 7) << 4;  // XOR on byte bits 4-6
  const int kvbase = w * 512;

  // ---- phase A: QK^T + exp + P->LDS over own kv quadrant ----
  float lsum = 0.f;
#pragma unroll 4
  for (int tt = 0; tt < 32; ++tt) {
    int kv = kvbase + tt * 16;
    bf16x8 kf0 = *(const bf16x8*)(Kh + (size_t)(kv + lr) * HD + 8 * g);
    bf16x8 kf1 = *(const bf16x8*)(Kh + (size_t)(kv + lr) * HD + 32 + 8 * g);
    f32x4 s = {};
    s = mfma_bf16(kf0, qf0, s);  // D[kv][q]: lane holds q=lr, kv=tt*16+4g+r
    s = mfma_bf16(kf1, qf1, s);
    float p0 = __builtin_amdgcn_exp2f(s[0] * SC2);
    float p1 = __builtin_amdgcn_exp2f(s[1] * SC2);
    float p2 = __builtin_amdgcn_exp2f(s[2] * SC2);
    float p3 = __builtin_amdgcn_exp2f(s[3] * SC2);
    lsum += (p0 + p1) + (p2 + p3);
    u64 u = (u64)bfbits(p0) | ((u64)bfbits(p1) << 16) | ((u64)bfbits(p2) << 32)
          | ((u64)bfbits(p3) << 48);
    *reinterpret_cast<u64*>(myt + lr * 1024 + ((tt * 32 + g * 8) ^ pswz)) = u;
  }
  lsum += __shfl_xor(lsum, 16);
  lsum += __shfl_xor(lsum, 32);
  if (l < 16) lred[w][l] = lsum;
  __syncthreads();

  if (t < 16) linv[t] = 1.0f / (lred[0][t] + lred[1][t] + lred[2][t] + lred[3][t]);

  // ---- phase B: PV from own tile (unnormalized) ----
  f32x4 o[4] = {};
#pragma unroll 4
  for (int ks = 0; ks < 16; ++ks) {
    bf16x8 pf = *(const bf16x8*)(myt + lr * 1024 + ((ks * 64 + g * 16) ^ pswz));
#pragma unroll
    for (int dvt = 0; dvt < 4; ++dvt) {
      bf16x8 vf = *(const bf16x8*)(Vh + (size_t)(dvt * 16 + lr) * S_LEN + kvbase + ks * 32 + 8 * g);
      o[dvt] = mfma_bf16(pf, vf, o[dvt]);
    }
  }
  __syncthreads();  // all P tiles + linv visible

  // ---- phase C: stream attn rows 4w..4w+3, each row 8KB sequential ----
#pragma unroll
  for (int i = 0; i < 4; ++i) {
    int row = 4 * w + i;
    float inv = linv[row];
    float* base = attn + ((size_t)bh * S_LEN + q0 + row) * S_LEN;
    const int rswz = (row & 7) << 4;
#pragma unroll
    for (int c = 0; c < 8; ++c) {
      const char* src = &ptile[c >> 1][0] + row * 1024 + (((c & 1) * 512 + l * 8) ^ rswz);
      u64 v = *reinterpret_cast<const u64*>(src);
      unsigned lo = (unsigned)v, hi = (unsigned)(v >> 32);
      f32x4 pv;
      pv[0] = asf(lo << 16) * inv;
      pv[1] = asf(lo & 0xffff0000u) * inv;
      pv[2] = asf(hi << 16) * inv;
      pv[3] = asf(hi & 0xffff0000u) * inv;
      __builtin_nontemporal_store(pv, (f32x4*)(base + c * 256 + l * 4));
    }
  }

  // ---- phase D: cross-wave o reduce, ctx write ----
  if (w) {
#pragma unroll
    for (int dvt = 0; dvt < 4; ++dvt) obuf[w - 1][l][dvt] = o[dvt];
  }
  __syncthreads();
  if (w == 0) {
#pragma unroll
    for (int dvt = 0; dvt < 4; ++dvt) {
      f32x4 s0 = obuf[0][l][dvt], s1 = obuf[1][l][dvt], s2 = obuf[2][l][dvt];
#pragma unroll
      for (int r = 0; r < 4; ++r) {
        int q = q0 + g * 4 + r;
        float val = (o[dvt][r] + s0[r] + s1[r] + s2[r]) * linv[g * 4 + r];
        size_t idx = ((size_t)b * S_LEN + q) * DMODEL + h * HD + dvt * 16 + lr;
        ctx[idx] = __float2bfloat16(val);
      }
    }
  }
}

// ---------------- LayerNorm over rows of 1024 ----------------
__global__ __launch_bounds__(256) void k_ln(const float* __restrict__ x,
                                            const float* __restrict__ gam,
                                            const float* __restrict__ bet,
                                            float* __restrict__ y) {
  const int row = blockIdx.x;
  const int i = threadIdx.x * 4;
  const float* xr = x + (size_t)row * DMODEL;
  f32x4 v = *(const f32x4*)(xr + i);
  float s = v[0] + v[1] + v[2] + v[3];
  float s2 = v[0] * v[0] + v[1] * v[1] + v[2] * v[2] + v[3] * v[3];
#pragma unroll
  for (int off = 1; off < 64; off <<= 1) {
    s += __shfl_xor(s, off);
    s2 += __shfl_xor(s2, off);
  }
  __shared__ float red[2][4];
  const int w = threadIdx.x >> 6, ln = threadIdx.x & 63;
  if (ln == 0) { red[0][w] = s; red[1][w] = s2; }
  __syncthreads();
  s = red[0][0] + red[0][1] + red[0][2] + red[0][3];
  s2 = red[1][0] + red[1][1] + red[1][2] + red[1][3];
  const float mu = s * (1.f / DMODEL);
  const float rstd = rsqrtf(s2 * (1.f / DMODEL) - mu * mu + 1e-6f);
  f32x4 gv = *(const f32x4*)(gam + i), bv = *(const f32x4*)(bet + i);
  f32x4 out;
#pragma unroll
  for (int j = 0; j < 4; ++j) out[j] = (v[j] - mu) * rstd * gv[j] + bv[j];
  *(f32x4*)(y + (size_t)row * DMODEL + i) = out;
}

extern "C" void kernel_launch(void* const* d_in, const int* in_sizes, int n_in,
                              void* d_out, int out_size, void* d_ws, size_t ws_size,
                              hipStream_t stream) {
  const float* ip  = (const float*)d_in[0];
  const float* wk  = (const float*)d_in[1];
  const float* wq  = (const float*)d_in[2];
  const float* wv  = (const float*)d_in[3];
  const float* fcw = (const float*)d_in[4];
  const float* fcb = (const float*)d_in[5];
  const float* lng = (const float*)d_in[6];
  const float* lnb = (const float*)d_in[7];

  float* y = (float*)d_out;
  float* attn = y + (size_t)2 * S_LEN * DMODEL;  // outputs concatenated (y, attn)

  char* ws = (char*)d_ws;
  __hip_bfloat16* ipb = (__hip_bfloat16*)(ws);                  //  8 MB: ip bf16
  __hip_bfloat16* wt  = (__hip_bfloat16*)(ws + (8ll << 20));    //  6 MB: [wq^T|wk^T|wv^T]
  __hip_bfloat16* fct = (__hip_bfloat16*)(ws + (14ll << 20));   //  2 MB: fc_w^T
  __hip_bfloat16* Qb  = (__hip_bfloat16*)(ws + (16ll << 20));   //  8 MB: Q [32 bh][2048][64]
  __hip_bfloat16* Kb  = (__hip_bfloat16*)(ws + (24ll << 20));   //  8 MB: K
  __hip_bfloat16* Vb  = (__hip_bfloat16*)(ws + (32ll << 20));   //  8 MB: V
  __hip_bfloat16* Vtb = (__hip_bfloat16*)(ws + (40ll << 20));   //  8 MB: V^T [32 bh][64][2048]
  __hip_bfloat16* ctx = (__hip_bfloat16*)(ws + (48ll << 20));   //  8 MB: ctx
  float* preln        = (float*)(ws + (56ll << 20));            // 16 MB: pre-LN f32

  k_convert_ip<<<4096, 256, 0, stream>>>(ip, ipb, 2 * S_LEN * DMODEL);
  k_transpose_w<<<dim3(32, 32, 4), dim3(32, 32), 0, stream>>>(wq, wk, wv, fcw, wt, fct);
  k_gemm<0><<<32 * 24, 256, 0, stream>>>(ipb, wt, Qb, Kb, Vb, nullptr, nullptr, nullptr);
  k_transpose_v<<<dim3(64, 2, 32), dim3(32, 32), 0, stream>>>((const unsigned short*)Vb,
                                                              (unsigned short*)Vtb);
  k_attn2<<<4096, 256, 0, stream>>>(Qb, Kb, Vtb, attn, ctx);
  k_gemm<1><<<32 * 8, 256, 0, stream>>>(ctx, fct, nullptr, nullptr, nullptr, ip, fcb, preln);
  k_ln<<<4096, 256, 0, stream>>>(preln, lng, lnb, y);
}

// Round 5
// 343.869 us; speedup vs baseline: 1.4439x; 1.0263x over previous
//
#include <hip/hip_runtime.h>
#include <hip/hip_bf16.h>
#include <stdint.h>

#define S_LEN 2048
#define DMODEL 1024
#define NH 16
#define HD 64
// scale: 1/sqrt(64) folded with log2(e) for v_exp_f32 (exp2)
#define SC2 0.18033688011112042f

typedef __attribute__((ext_vector_type(8))) short bf16x8;
typedef __attribute__((ext_vector_type(4))) float f32x4;
typedef unsigned long long u64;

__device__ __forceinline__ void gload16(const void* g, void* l) {
  __builtin_amdgcn_global_load_lds(
      reinterpret_cast<const __attribute__((address_space(1))) void*>(reinterpret_cast<uintptr_t>(g)),
      reinterpret_cast<__attribute__((address_space(3))) void*>(reinterpret_cast<uintptr_t>(l)),
      16, 0, 0);
}

__device__ __forceinline__ f32x4 mfma_bf16(bf16x8 a, bf16x8 b, f32x4 c) {
  return __builtin_amdgcn_mfma_f32_16x16x32_bf16(a, b, c, 0, 0, 0);
}

__device__ __forceinline__ unsigned short bfbits(float x) {
  __hip_bfloat16 h = __float2bfloat16(x);
  return *reinterpret_cast<unsigned short*>(&h);
}

__device__ __forceinline__ float asf(unsigned u) {
  union { unsigned u; float f; } c; c.u = u; return c.f;
}

// Barrier that waits only on LDS ops (lgkmcnt), NOT on in-flight global
// stores (vmcnt). All cross-wave deps in k_attn3 are LDS-only; __syncthreads
// would drain the NT store queue at every phase boundary (the R4 stall).
__device__ __forceinline__ void bar_lgkm() {
  __builtin_amdgcn_sched_barrier(0);
  asm volatile("s_waitcnt lgkmcnt(0)" ::: "memory");
  __builtin_amdgcn_sched_barrier(0);
  __builtin_amdgcn_s_barrier();
  __builtin_amdgcn_sched_barrier(0);
}

// ---------------- convert ip f32 -> bf16 ----------------
__global__ __launch_bounds__(256) void k_convert_ip(const float* __restrict__ in,
                                                    __hip_bfloat16* __restrict__ out, int n) {
  int i = (blockIdx.x * 256 + threadIdx.x) * 4;
  if (i >= n) return;
  f32x4 v = *(const f32x4*)(in + i);
  u64 p = (u64)bfbits(v[0]) | ((u64)bfbits(v[1]) << 16) | ((u64)bfbits(v[2]) << 32)
        | ((u64)bfbits(v[3]) << 48);
  *reinterpret_cast<u64*>(out + i) = p;
}

// ---------------- transpose+convert weights: out[n][k] = in[k][n] (1024x1024) ----------------
__global__ __launch_bounds__(1024) void k_transpose_w(const float* __restrict__ wq,
                                                      const float* __restrict__ wk,
                                                      const float* __restrict__ wv,
                                                      const float* __restrict__ fcw,
                                                      __hip_bfloat16* __restrict__ wt_all,
                                                      __hip_bfloat16* __restrict__ fct) {
  __shared__ float tile[32][33];
  const int z = blockIdx.z;
  const float* src = (z == 0) ? wq : (z == 1) ? wk : (z == 2) ? wv : fcw;
  __hip_bfloat16* dst = (z == 3) ? fct : wt_all + (size_t)z * DMODEL * DMODEL;
  const int kb = blockIdx.y * 32, nb = blockIdx.x * 32;
  tile[threadIdx.y][threadIdx.x] = src[(size_t)(kb + threadIdx.y) * DMODEL + nb + threadIdx.x];
  __syncthreads();
  dst[(size_t)(nb + threadIdx.y) * DMODEL + kb + threadIdx.x] =
      __float2bfloat16(tile[threadIdx.x][threadIdx.y]);
}

// ---------------- transpose V [bh][s][d] -> Vt [bh][d][s] (bf16) ----------------
__global__ __launch_bounds__(1024) void k_transpose_v(const unsigned short* __restrict__ V,
                                                      unsigned short* __restrict__ Vt) {
  __shared__ unsigned short tile[32][33];
  const int bh = blockIdx.z;
  const int sb = blockIdx.x * 32, db = blockIdx.y * 32;
  const unsigned short* src = V + (size_t)bh * S_LEN * HD;
  unsigned short* dst = Vt + (size_t)bh * HD * S_LEN;
  tile[threadIdx.y][threadIdx.x] = src[(size_t)(sb + threadIdx.y) * HD + db + threadIdx.x];
  __syncthreads();
  dst[(size_t)(db + threadIdx.y) * S_LEN + sb + threadIdx.x] = tile[threadIdx.x][threadIdx.y];
}

// ---------------- bf16 GEMM, 128x128 tile, BK=32, 4 waves (m97 structure) ----------------
template <int MODE>
__global__ __launch_bounds__(256) void k_gemm(const __hip_bfloat16* __restrict__ A,
                                              const __hip_bfloat16* __restrict__ Bt,
                                              __hip_bfloat16* __restrict__ Q,
                                              __hip_bfloat16* __restrict__ Kk,
                                              __hip_bfloat16* __restrict__ V,
                                              const float* __restrict__ ipf,
                                              const float* __restrict__ bias,
                                              float* __restrict__ preln) {
  __shared__ __align__(128) char lds[16384];
  char* Al = lds;
  char* Bl = lds + 8192;
  const int t = threadIdx.x;
  const int w = t >> 6, l = t & 63;
  const int g = l >> 4, lr = l & 15;
  const int bm = blockIdx.x & 31;
  const int bn = blockIdx.x >> 5;

  int sr0 = (w * 2 + 0) * 16 + (l >> 2);
  int sr1 = (w * 2 + 1) * 16 + (l >> 2);
  const int sc = (l & 3) * 16;
  const char* aSrc0 = (const char*)A + ((size_t)(bm * 128 + sr0)) * 2048 + (sc ^ (((sr0 >> 1) & 3) << 4));
  const char* aSrc1 = (const char*)A + ((size_t)(bm * 128 + sr1)) * 2048 + (sc ^ (((sr1 >> 1) & 3) << 4));
  const char* bSrc0 = (const char*)Bt + ((size_t)(bn * 128 + sr0)) * 2048 + (sc ^ (((sr0 >> 1) & 3) << 4));
  const char* bSrc1 = (const char*)Bt + ((size_t)(bn * 128 + sr1)) * 2048 + (sc ^ (((sr1 >> 1) & 3) << 4));

  const int wm = (w >> 1) * 64, wn = (w & 1) * 64;
  int roff[4], noff[4];
#pragma unroll
  for (int mi = 0; mi < 4; ++mi) {
    int m = wm + mi * 16 + lr;
    roff[mi] = m * 64 + ((g * 16) ^ (((m >> 1) & 3) << 4));
  }
#pragma unroll
  for (int ni = 0; ni < 4; ++ni) {
    int n = wn + ni * 16 + lr;
    noff[ni] = n * 64 + ((g * 16) ^ (((n >> 1) & 3) << 4));
  }

  f32x4 acc[4][4] = {};
  for (int k0 = 0; k0 < DMODEL; k0 += 32) {
    gload16(aSrc0 + k0 * 2, Al + (w * 2 + 0) * 1024);
    gload16(aSrc1 + k0 * 2, Al + (w * 2 + 1) * 1024);
    gload16(bSrc0 + k0 * 2, Bl + (w * 2 + 0) * 1024);
    gload16(bSrc1 + k0 * 2, Bl + (w * 2 + 1) * 1024);
    __syncthreads();
    bf16x8 af[4], bfv[4];
#pragma unroll
    for (int mi = 0; mi < 4; ++mi) af[mi] = *(const bf16x8*)(Al + roff[mi]);
#pragma unroll
    for (int ni = 0; ni < 4; ++ni) bfv[ni] = *(const bf16x8*)(Bl + noff[ni]);
#pragma unroll
    for (int mi = 0; mi < 4; ++mi)
#pragma unroll
      for (int ni = 0; ni < 4; ++ni)
        acc[mi][ni] = mfma_bf16(af[mi], bfv[ni], acc[mi][ni]);
    __syncthreads();
  }

#pragma unroll
  for (int mi = 0; mi < 4; ++mi)
#pragma unroll
    for (int ni = 0; ni < 4; ++ni) {
      f32x4 v = acc[mi][ni];
#pragma unroll
      for (int r = 0; r < 4; ++r) {
        int m = bm * 128 + wm + mi * 16 + g * 4 + r;
        int n = bn * 128 + wn + ni * 16 + lr;
        if (MODE == 0) {
          int mat = n >> 10, c = n & 1023;
          int h = c >> 6, d = c & 63;
          int b = m >> 11, s = m & 2047;
          size_t idx = (((size_t)(b * NH + h)) * S_LEN + s) * HD + d;
          __hip_bfloat16 hv = __float2bfloat16(v[r]);
          if (mat == 0) Q[idx] = hv;
          else if (mat == 1) Kk[idx] = hv;
          else V[idx] = hv;
        } else {
          size_t idx = (size_t)m * DMODEL + n;
          preln[idx] = v[r] + bias[n] + ipf[idx];
        }
      }
    }
}

// ---------------- fused attention, persistent one-pass ----------------
// 512 blocks (2/CU), each owns one (b,h) and processes 8 q-chunks of 16 rows.
// Per item: phase A: wave w computes QK^T/exp over kv quadrant [w*512,+512),
// P(bf16)->LDS, lsum online (no max). bar. linv. bar. phase C: stream attn
// rows 4w..4w+3 as sequential NT stores (issued EARLY, left in flight).
// phase B: PV from own tile. obuf partials. bar. w0 reduces -> ctx.
// ALL barriers are lgkm-only: NT stores from item i drain during item i+1's
// compute instead of stalling at every __syncthreads (the R4 bottleneck).
__global__ __launch_bounds__(256, 2) void k_attn3(const __hip_bfloat16* __restrict__ Q,
                                                  const __hip_bfloat16* __restrict__ K,
                                                  const __hip_bfloat16* __restrict__ Vt,
                                                  float* __restrict__ attn,
                                                  __hip_bfloat16* __restrict__ ctx) {
  __shared__ __align__(128) char ptile[4][16384];  // [wave][16 q][1024B], XOR-swizzled rows
  __shared__ float lred[4][16];
  __shared__ float linv[16];
  __shared__ f32x4 obuf[3][64][4];  // 12KB cross-wave o partials

  const int t = threadIdx.x, w = t >> 6, l = t & 63;
  const int g = l >> 4, lr = l & 15;
  const int bid = blockIdx.x;                    // 0..511
  const int bh = (bid & 7) + 8 * (bid >> 7);     // XCD (bid&7) serves bh = x,8+x,16+x,24+x
  const int qgrp = (bid >> 3) & 15;              // 16 blocks per bh
  const int b = bh >> 4, h = bh & 15;
  const __hip_bfloat16* Qh = Q + (size_t)bh * S_LEN * HD;
  const __hip_bfloat16* Kh = K + (size_t)bh * S_LEN * HD;
  const __hip_bfloat16* Vh = Vt + (size_t)bh * HD * S_LEN;

  char* myt = &ptile[w][0];
  const int pswz = (lr & 7) << 4;  // XOR on byte bits 4-6
  const int kvbase = w * 512;

  for (int item = 0; item < 8; ++item) {
    const int q0 = (qgrp * 8 + item) * 16;
    bf16x8 qf0 = *(const bf16x8*)(Qh + (size_t)(q0 + lr) * HD + 8 * g);
    bf16x8 qf1 = *(const bf16x8*)(Qh + (size_t)(q0 + lr) * HD + 32 + 8 * g);

    // ---- phase A: QK^T + exp + P->LDS over own kv quadrant ----
    float lsum = 0.f;
#pragma unroll 4
    for (int tt = 0; tt < 32; ++tt) {
      int kv = kvbase + tt * 16;
      bf16x8 kf0 = *(const bf16x8*)(Kh + (size_t)(kv + lr) * HD + 8 * g);
      bf16x8 kf1 = *(const bf16x8*)(Kh + (size_t)(kv + lr) * HD + 32 + 8 * g);
      f32x4 s = {};
      s = mfma_bf16(kf0, qf0, s);  // D[kv][q]: lane holds q=lr, kv=tt*16+4g+r
      s = mfma_bf16(kf1, qf1, s);
      float p0 = __builtin_amdgcn_exp2f(s[0] * SC2);
      float p1 = __builtin_amdgcn_exp2f(s[1] * SC2);
      float p2 = __builtin_amdgcn_exp2f(s[2] * SC2);
      float p3 = __builtin_amdgcn_exp2f(s[3] * SC2);
      lsum += (p0 + p1) + (p2 + p3);
      u64 u = (u64)bfbits(p0) | ((u64)bfbits(p1) << 16) | ((u64)bfbits(p2) << 32)
            | ((u64)bfbits(p3) << 48);
      *reinterpret_cast<u64*>(myt + lr * 1024 + ((tt * 32 + g * 8) ^ pswz)) = u;
    }
    lsum += __shfl_xor(lsum, 16);
    lsum += __shfl_xor(lsum, 32);
    if (l < 16) lred[w][l] = lsum;
    bar_lgkm();

    if (t < 16) linv[t] = 1.0f / (lred[0][t] + lred[1][t] + lred[2][t] + lred[3][t]);
    bar_lgkm();

    // ---- phase C: stream attn rows 4w..4w+3 (8KB sequential each), NT ----
    // Issued BEFORE PV so the stores drain under the following compute.
#pragma unroll
    for (int i = 0; i < 4; ++i) {
      int row = 4 * w + i;
      float inv = linv[row];
      float* base = attn + ((size_t)bh * S_LEN + q0 + row) * S_LEN;
      const int rswz = (row & 7) << 4;
#pragma unroll
      for (int c = 0; c < 8; ++c) {
        const char* src = &ptile[c >> 1][0] + row * 1024 + (((c & 1) * 512 + l * 8) ^ rswz);
        u64 v = *reinterpret_cast<const u64*>(src);
        unsigned lo = (unsigned)v, hi = (unsigned)(v >> 32);
        f32x4 pv;
        pv[0] = asf(lo << 16) * inv;
        pv[1] = asf(lo & 0xffff0000u) * inv;
        pv[2] = asf(hi << 16) * inv;
        pv[3] = asf(hi & 0xffff0000u) * inv;
        __builtin_nontemporal_store(pv, (f32x4*)(base + c * 256 + l * 4));
      }
    }

    // ---- phase B: PV from own tile (unnormalized) ----
    f32x4 o[4] = {};
#pragma unroll 4
    for (int ks = 0; ks < 16; ++ks) {
      bf16x8 pf = *(const bf16x8*)(myt + lr * 1024 + ((ks * 64 + g * 16) ^ pswz));
#pragma unroll
      for (int dvt = 0; dvt < 4; ++dvt) {
        bf16x8 vf = *(const bf16x8*)(Vh + (size_t)(dvt * 16 + lr) * S_LEN + kvbase + ks * 32 + 8 * g);
        o[dvt] = mfma_bf16(pf, vf, o[dvt]);
      }
    }
    if (w) {
#pragma unroll
      for (int dvt = 0; dvt < 4; ++dvt) obuf[w - 1][l][dvt] = o[dvt];
    }
    bar_lgkm();  // ptile reads (C) + obuf writes done -> next A may overwrite ptile

    // ---- phase D: w0 reduces + writes ctx while other waves start next item ----
    if (w == 0) {
#pragma unroll
      for (int dvt = 0; dvt < 4; ++dvt) {
        f32x4 s0 = obuf[0][l][dvt], s1 = obuf[1][l][dvt], s2 = obuf[2][l][dvt];
#pragma unroll
        for (int r = 0; r < 4; ++r) {
          int q = q0 + g * 4 + r;
          float val = (o[dvt][r] + s0[r] + s1[r] + s2[r]) * linv[g * 4 + r];
          size_t idx = ((size_t)b * S_LEN + q) * DMODEL + h * HD + dvt * 16 + lr;
          ctx[idx] = __float2bfloat16(val);
        }
      }
    }
    bar_lgkm();  // protect obuf/linv from next item's writers
  }
}

// ---------------- LayerNorm over rows of 1024 ----------------
__global__ __launch_bounds__(256) void k_ln(const float* __restrict__ x,
                                            const float* __restrict__ gam,
                                            const float* __restrict__ bet,
                                            float* __restrict__ y) {
  const int row = blockIdx.x;
  const int i = threadIdx.x * 4;
  const float* xr = x + (size_t)row * DMODEL;
  f32x4 v = *(const f32x4*)(xr + i);
  float s = v[0] + v[1] + v[2] + v[3];
  float s2 = v[0] * v[0] + v[1] * v[1] + v[2] * v[2] + v[3] * v[3];
#pragma unroll
  for (int off = 1; off < 64; off <<= 1) {
    s += __shfl_xor(s, off);
    s2 += __shfl_xor(s2, off);
  }
  __shared__ float red[2][4];
  const int w = threadIdx.x >> 6, ln = threadIdx.x & 63;
  if (ln == 0) { red[0][w] = s; red[1][w] = s2; }
  __syncthreads();
  s = red[0][0] + red[0][1] + red[0][2] + red[0][3];
  s2 = red[1][0] + red[1][1] + red[1][2] + red[1][3];
  const float mu = s * (1.f / DMODEL);
  const float rstd = rsqrtf(s2 * (1.f / DMODEL) - mu * mu + 1e-6f);
  f32x4 gv = *(const f32x4*)(gam + i), bv = *(const f32x4*)(bet + i);
  f32x4 out;
#pragma unroll
  for (int j = 0; j < 4; ++j) out[j] = (v[j] - mu) * rstd * gv[j] + bv[j];
  *(f32x4*)(y + (size_t)row * DMODEL + i) = out;
}

extern "C" void kernel_launch(void* const* d_in, const int* in_sizes, int n_in,
                              void* d_out, int out_size, void* d_ws, size_t ws_size,
                              hipStream_t stream) {
  const float* ip  = (const float*)d_in[0];
  const float* wk  = (const float*)d_in[1];
  const float* wq  = (const float*)d_in[2];
  const float* wv  = (const float*)d_in[3];
  const float* fcw = (const float*)d_in[4];
  const float* fcb = (const float*)d_in[5];
  const float* lng = (const float*)d_in[6];
  const float* lnb = (const float*)d_in[7];

  float* y = (float*)d_out;
  float* attn = y + (size_t)2 * S_LEN * DMODEL;  // outputs concatenated (y, attn)

  char* ws = (char*)d_ws;
  __hip_bfloat16* ipb = (__hip_bfloat16*)(ws);                  //  8 MB: ip bf16
  __hip_bfloat16* wt  = (__hip_bfloat16*)(ws + (8ll << 20));    //  6 MB: [wq^T|wk^T|wv^T]
  __hip_bfloat16* fct = (__hip_bfloat16*)(ws + (14ll << 20));   //  2 MB: fc_w^T
  __hip_bfloat16* Qb  = (__hip_bfloat16*)(ws + (16ll << 20));   //  8 MB: Q [32 bh][2048][64]
  __hip_bfloat16* Kb  = (__hip_bfloat16*)(ws + (24ll << 20));   //  8 MB: K
  __hip_bfloat16* Vb  = (__hip_bfloat16*)(ws + (32ll << 20));   //  8 MB: V
  __hip_bfloat16* Vtb = (__hip_bfloat16*)(ws + (40ll << 20));   //  8 MB: V^T [32 bh][64][2048]
  __hip_bfloat16* ctx = (__hip_bfloat16*)(ws + (48ll << 20));   //  8 MB: ctx
  float* preln        = (float*)(ws + (56ll << 20));            // 16 MB: pre-LN f32

  k_convert_ip<<<4096, 256, 0, stream>>>(ip, ipb, 2 * S_LEN * DMODEL);
  k_transpose_w<<<dim3(32, 32, 4), dim3(32, 32), 0, stream>>>(wq, wk, wv, fcw, wt, fct);
  k_gemm<0><<<32 * 24, 256, 0, stream>>>(ipb, wt, Qb, Kb, Vb, nullptr, nullptr, nullptr);
  k_transpose_v<<<dim3(64, 2, 32), dim3(32, 32), 0, stream>>>((const unsigned short*)Vb,
                                                              (unsigned short*)Vtb);
  k_attn3<<<512, 256, 0, stream>>>(Qb, Kb, Vtb, attn, ctx);
  k_gemm<1><<<32 * 8, 256, 0, stream>>>(ctx, fct, nullptr, nullptr, nullptr, ip, fcb, preln);
  k_ln<<<4096, 256, 0, stream>>>(preln, lng, lnb, y);
}